// Round 10
// baseline (143.394 us; speedup 1.0000x reference)
//
#include <hip/hip_runtime.h>
#include <math.h>

// x: [64, 256, 32, 32] fp32. 2-kernel pipeline (kernel boundary = grid sync),
// zero global atomics, no cooperative launch (r9 lesson: container died):
//  S : 2048 blocks x 256 — per-block partial sums + |x|>=T candidates into a
//      PRIVATE per-block region (plain stores).
//  SA: 2048 blocks x 256 — each block REDUNDANTLY (8x/channel) computes
//      mean -> validity (exact proof) -> 3-level radix select + topK-sum,
//      gathering candidates from L2 each pass (no LDS staging, 16.5 KB LDS
//      -> 8 blocks/CU); exact global fallback; then applies its 8 slabs.
#define C_DIM    256
#define N_DIM    64
#define M_DIM    65536
#define K_TOP    100
#define EPS_F    1e-7f
#define THREADS  256
#define NWAVES   4
#define T_FAST   2.5f           // candidate threshold; validity checked exactly
#define SBLOCKS  2048
#define GRPS     8              // S-blocks (regions) per channel
#define LCAP     768u           // per-block candidate cap (expect ~100)

// ws layout (bytes)
#define WS_PART_OFF  0          // 2048 dbl  per-S-block partial sums  (16 KB)
#define WS_BCNT_OFF  16384      // 2048 u32  per-S-block candidate counts (8 KB)
#define WS_CAND_OFF  32768      // 2048 * bcap u32 private candidate regions

typedef float f4v __attribute__((ext_vector_type(4)));

// Wave-aggregated LDS append: pred lanes write bits to buf in lane order.
__device__ __forceinline__ void wave_append(
    bool pred, unsigned int bits, unsigned int* buf, unsigned int cap,
    unsigned int* counter, int lane)
{
    unsigned long long mask = __ballot(pred);
    if (mask == 0ull) return;                     // wave-uniform early out
    const int leader = __ffsll((unsigned long long)mask) - 1;
    unsigned int wbase = 0u;
    if (lane == leader) wbase = atomicAdd(counter, (unsigned int)__popcll(mask));
    wbase = __shfl(wbase, leader, 64);
    if (pred) {
        unsigned int p = wbase + (unsigned int)__popcll(mask & ((1ull << lane) - 1ull));
        if (p < cap) buf[p] = bits;
    }
}

__device__ __forceinline__ unsigned int wave_suffix_u32(unsigned int v, int lane)
{
    #pragma unroll
    for (int off = 1; off < 64; off <<= 1) {
        unsigned int o = __shfl_down(v, off, 64);
        if (lane + off < 64) v += o;
    }
    return v;
}

__device__ __forceinline__ double block_sum_double(double v, double* dred, int tid)
{
    const int lane = tid & 63, wv = tid >> 6;
    #pragma unroll
    for (int off = 1; off < 64; off <<= 1) {
        double o = __shfl_down(v, off, 64);
        if (lane + off < 64) v += o;
    }
    __syncthreads();
    if (lane == 0) dred[wv] = v;
    __syncthreads();
    double r = 0.0;
    if (tid == 0) {
        #pragma unroll
        for (int i = 0; i < NWAVES; ++i) r += dred[i];
    }
    return r;   // valid on tid 0 only
}

// Find, in hist[0..nbins) (ascending bins), the bin holding the Krem-th
// largest element; write bin + count-strictly-above into LDS outs.
__device__ __forceinline__ void select_bin(
    const unsigned int* hist, int nbins, unsigned int Krem,
    unsigned int* wtot, unsigned int* wsuf,
    unsigned int* out_bin, unsigned int* out_cnt, int tid)
{
    const int lane = tid & 63, wv = tid >> 6;
    const int bpt = (nbins + THREADS - 1) / THREADS;
    const int lo = tid * bpt;
    const int hi = min(nbins, lo + bpt);
    unsigned int s = 0;
    for (int b = lo; b < hi; ++b) s += hist[b];
    const unsigned int ws = wave_suffix_u32(s, lane);
    if (lane == 0) wtot[wv] = ws;
    __syncthreads();
    if (tid < NWAVES) {
        unsigned int t2 = 0;
        for (int j = tid; j < NWAVES; ++j) t2 += wtot[j];
        wsuf[tid] = t2;
    }
    __syncthreads();
    const unsigned int above_w = (wv + 1 < NWAVES) ? wsuf[wv + 1] : 0u;
    const unsigned int incl   = ws + above_w;
    const unsigned int S_excl = incl - s;
    if (S_excl < Krem && incl >= Krem) {     // exactly one thread
        unsigned int cum = S_excl;
        for (int b = hi - 1; b >= lo; --b) {
            unsigned int h = hist[b];
            if (cum + h >= Krem) { *out_bin = (unsigned int)b; *out_cnt = cum; break; }
            cum += h;
        }
    }
    __syncthreads();
}

// ---------------------------------------------------------------------------
// S: block b -> channel c=b&255, slabs n=8g..8g+7 (g=b>>8).
// Candidates -> LDS -> private region candbuf[b*bcap]; count -> bcnt[b].
// ---------------------------------------------------------------------------
__global__ __launch_bounds__(THREADS) void stats_pass(
    const float4* __restrict__ x4, double* __restrict__ partial,
    unsigned int* __restrict__ bcnt, unsigned int* __restrict__ candbuf,
    unsigned int bcap)
{
    const int b = blockIdx.x;
    const int c = b & 255;
    const int g = b >> 8;
    const int t = threadIdx.x;
    const int lane = t & 63, wv = t >> 6;
    const unsigned int capw = (bcap < LCAP) ? bcap : LCAP;

    __shared__ double dred[NWAVES];
    __shared__ unsigned int lbuf[LCAP];
    __shared__ unsigned int s_lc;
    if (t == 0) s_lc = 0u;
    __syncthreads();

    double s = 0.0;
    #pragma unroll
    for (int j = 0; j < 8; ++j) {
        const int n = (g << 3) + j;
        const float4 q = x4[((size_t)((n << 8) + c) << 8) + t];
        s += ((double)q.x + (double)q.y) + ((double)q.z + (double)q.w);
        wave_append(fabsf(q.x) >= T_FAST, __float_as_uint(q.x), lbuf, capw, &s_lc, lane);
        wave_append(fabsf(q.y) >= T_FAST, __float_as_uint(q.y), lbuf, capw, &s_lc, lane);
        wave_append(fabsf(q.z) >= T_FAST, __float_as_uint(q.z), lbuf, capw, &s_lc, lane);
        wave_append(fabsf(q.w) >= T_FAST, __float_as_uint(q.w), lbuf, capw, &s_lc, lane);
    }
    #pragma unroll
    for (int off = 1; off < 64; off <<= 1) {
        double o = __shfl_down(s, off, 64);
        if (lane + off < 64) s += o;
    }
    if (lane == 0) dred[wv] = s;
    __syncthreads();
    if (t == 0) {
        partial[b] = (dred[0] + dred[1]) + (dred[2] + dred[3]);
        bcnt[b] = s_lc;                       // raw count (may exceed capw)
    }
    __syncthreads();
    const unsigned int lc = min(s_lc, capw);
    unsigned int* dst = candbuf + (size_t)b * bcap;
    for (unsigned int i = t; i < lc; i += THREADS) dst[i] = lbuf[i];
}

// Iterate all candidates of channel c (GRPS regions, L2-hot);
// u = bits of |v - mean|.
#define FOR_CANDS(UVAR, BODY) \
    for (int g2 = 0; g2 < GRPS; ++g2) { \
        const unsigned int cg_ = min(s_bc[g2], capw); \
        const unsigned int* src = candbuf + (size_t)((g2 << 8) + c) * bcap; \
        for (unsigned int i = t; i < cg_; i += THREADS) { \
            const unsigned int UVAR = \
                __float_as_uint(fabsf(__uint_as_float(src[i]) - mean)); \
            BODY \
        } \
    }

// ---------------------------------------------------------------------------
// SA: block b -> channel c=b&255, slabs 8g..8g+7. Redundant select + apply.
// ---------------------------------------------------------------------------
__global__ __launch_bounds__(THREADS) void select_apply(
    const float4* __restrict__ x4, const double* __restrict__ partial,
    const unsigned int* __restrict__ bcnt, const unsigned int* __restrict__ candbuf,
    unsigned int bcap,
    const float* __restrict__ weight, const float* __restrict__ bias,
    float4* __restrict__ out4, float cconst)
{
    const int b = blockIdx.x;
    const int c = b & 255;
    const int g = b >> 8;
    const int t = threadIdx.x;
    const unsigned int capw = (bcap < LCAP) ? bcap : LCAP;

    __shared__ unsigned int hist[4096];
    __shared__ unsigned int wtot[NWAVES], wsuf[NWAVES];
    __shared__ double dred[8];
    __shared__ float s_mean, s_alpha, s_beta;
    __shared__ unsigned int s_bin, s_cnt, s_nB;
    __shared__ unsigned int s_bc[GRPS];

    if (t < GRPS) s_bc[t] = bcnt[(t << 8) + c];
    if (t < 8) dred[t] = partial[(t << 8) + c];
    if (t == 0) s_nB = 0u;
    __syncthreads();
    if (t == 0) {
        double m = 0.0;
        #pragma unroll
        for (int i = 0; i < 8; ++i) m += dred[i];
        s_mean = (float)(m / (double)M_DIM);
    }
    __syncthreads();
    const float mean = s_mean;
    const float Babs = T_FAST + fabsf(mean);
    const unsigned int Bbits = __float_as_uint(Babs);

    bool fast = true;
    #pragma unroll
    for (int gg = 0; gg < GRPS; ++gg) if (s_bc[gg] > capw) fast = false;

    if (fast) {
        // Validity: non-collected values have |x-mean| < Babs; if >= K
        // collected values strictly exceed Babs, top-K is fully collected.
        unsigned int loc = 0;
        FOR_CANDS(u, { if (u > Bbits) ++loc; })
        if (loc) atomicAdd(&s_nB, loc);
        __syncthreads();
        fast = (s_nB >= K_TOP);
    }

    unsigned int vk_bits, cnt_gt;
    double sum_gt;

    if (fast) {
        // ---- 3-level radix select, candidates gathered from L2 each pass ----
        #pragma unroll
        for (int i = 0; i < 16; ++i) hist[t + (i << 8)] = 0u;
        __syncthreads();
        FOR_CANDS(u, { atomicAdd(&hist[u >> 20], 1u); })
        __syncthreads();
        select_bin(hist, 4096, K_TOP, wtot, wsuf, &s_bin, &s_cnt, t);
        const unsigned int b1 = s_bin;
        cnt_gt = s_cnt;
        const unsigned int K2 = K_TOP - s_cnt;

        #pragma unroll
        for (int i = 0; i < 16; ++i) hist[t + (i << 8)] = 0u;
        __syncthreads();
        FOR_CANDS(u, { if ((u >> 20) == b1) atomicAdd(&hist[(u >> 8) & 0xFFFu], 1u); })
        __syncthreads();
        select_bin(hist, 4096, K2, wtot, wsuf, &s_bin, &s_cnt, t);
        const unsigned int b2 = s_bin;
        const unsigned int K3 = K2 - s_cnt;
        const unsigned int pfx24 = (b1 << 12) | b2;
        cnt_gt += s_cnt;

        hist[t] = 0u;
        __syncthreads();
        FOR_CANDS(u, { if ((u >> 8) == pfx24) atomicAdd(&hist[u & 0xFFu], 1u); })
        __syncthreads();
        select_bin(hist, 256, K3, wtot, wsuf, &s_bin, &s_cnt, t);
        cnt_gt += s_cnt;
        vk_bits = (pfx24 << 8) | s_bin;

        double sg = 0.0;
        FOR_CANDS(u, { if (u > vk_bits) sg += (double)__uint_as_float(u); })
        sum_gt = block_sum_double(sg, dred, t);
    } else {
        // ---- exact fallback: 4-pass radix select from global (L3-hot) ----
        #pragma unroll
        for (int i = 0; i < 16; ++i) hist[t + (i << 8)] = 0u;
        __syncthreads();
        for (int nn = 0; nn < N_DIM; ++nn) {
            const float4 q = x4[((size_t)((nn << 8) + c) << 8) + t];
            const float vv[4] = {q.x, q.y, q.z, q.w};
            #pragma unroll
            for (int j = 0; j < 4; ++j)
                atomicAdd(&hist[__float_as_uint(fabsf(vv[j] - mean)) >> 20], 1u);
        }
        __syncthreads();
        select_bin(hist, 4096, K_TOP, wtot, wsuf, &s_bin, &s_cnt, t);
        const unsigned int b1 = s_bin;
        cnt_gt = s_cnt;
        const unsigned int K2 = K_TOP - s_cnt;

        #pragma unroll
        for (int i = 0; i < 16; ++i) hist[t + (i << 8)] = 0u;
        __syncthreads();
        for (int nn = 0; nn < N_DIM; ++nn) {
            const float4 q = x4[((size_t)((nn << 8) + c) << 8) + t];
            const float vv[4] = {q.x, q.y, q.z, q.w};
            #pragma unroll
            for (int j = 0; j < 4; ++j) {
                const unsigned int u = __float_as_uint(fabsf(vv[j] - mean));
                if ((u >> 20) == b1) atomicAdd(&hist[(u >> 8) & 0xFFFu], 1u);
            }
        }
        __syncthreads();
        select_bin(hist, 4096, K2, wtot, wsuf, &s_bin, &s_cnt, t);
        const unsigned int b2 = s_bin;
        const unsigned int K3 = K2 - s_cnt;
        const unsigned int pfx24 = (b1 << 12) | b2;
        cnt_gt += s_cnt;

        hist[t] = 0u;
        __syncthreads();
        for (int nn = 0; nn < N_DIM; ++nn) {
            const float4 q = x4[((size_t)((nn << 8) + c) << 8) + t];
            const float vv[4] = {q.x, q.y, q.z, q.w};
            #pragma unroll
            for (int j = 0; j < 4; ++j) {
                const unsigned int u = __float_as_uint(fabsf(vv[j] - mean));
                if ((u >> 8) == pfx24) atomicAdd(&hist[u & 0xFFu], 1u);
            }
        }
        __syncthreads();
        select_bin(hist, 256, K3, wtot, wsuf, &s_bin, &s_cnt, t);
        cnt_gt += s_cnt;
        vk_bits = (pfx24 << 8) | s_bin;

        double sg = 0.0;
        for (int nn = 0; nn < N_DIM; ++nn) {
            const float4 q = x4[((size_t)((nn << 8) + c) << 8) + t];
            const float vv[4] = {q.x, q.y, q.z, q.w};
            #pragma unroll
            for (int j = 0; j < 4; ++j) {
                const float a = fabsf(vv[j] - mean);
                if (__float_as_uint(a) > vk_bits) sg += (double)a;
            }
        }
        sum_gt = block_sum_double(sg, dred, t);
    }

    if (t == 0) {
        const float vK = __uint_as_float(vk_bits);
        const double top_sum = sum_gt + (double)(K_TOP - cnt_gt) * (double)vK;
        const float mean_topk = (float)(top_sum / (double)K_TOP) * cconst;
        const float scale = 1.0f / (mean_topk + EPS_F);
        const float a = scale * weight[c];
        s_alpha = a;
        s_beta  = bias[c] - mean * a;
    }
    __syncthreads();

    // ---- apply my 8 slabs: out = alpha*x + beta (x L3-hot) ----
    const float a = s_alpha, bb = s_beta;
    #pragma unroll
    for (int j = 0; j < 8; ++j) {
        const int n = (g << 3) + j;
        const size_t idx = ((size_t)((n << 8) + c) << 8) + t;
        const float4 q = x4[idx];
        f4v o;
        o[0] = fmaf(q.x, a, bb);
        o[1] = fmaf(q.y, a, bb);
        o[2] = fmaf(q.z, a, bb);
        o[3] = fmaf(q.w, a, bb);
        __builtin_nontemporal_store(o, (f4v*)(out4 + idx));
    }
}

// ---------------------------------------------------------------------------
extern "C" void kernel_launch(void* const* d_in, const int* in_sizes, int n_in,
                              void* d_out, int out_size, void* d_ws, size_t ws_size,
                              hipStream_t stream)
{
    const float* x = (const float*)d_in[0];
    const float* w = (const float*)d_in[1];
    const float* b = (const float*)d_in[2];
    float* out = (float*)d_out;

    double*  partial   = (double*)((char*)d_ws + WS_PART_OFF);
    unsigned int* bcnt = (unsigned int*)((char*)d_ws + WS_BCNT_OFF);
    unsigned int* cand = (unsigned int*)((char*)d_ws + WS_CAND_OFF);

    unsigned int bcap = LCAP;
    if (ws_size > WS_CAND_OFF) {
        const size_t avail = (ws_size - WS_CAND_OFF) / ((size_t)SBLOCKS * sizeof(unsigned int));
        if (avail < bcap) bcap = (unsigned int)avail;
    } else {
        bcap = 0;
    }

    const int M = in_sizes[0] / in_sizes[1];   // 65536
    const double cst = 0.5 * (1.0 + sqrt(M_PI * log(4.0))) / sqrt(2.0 * log((double)M));

    stats_pass<<<SBLOCKS, THREADS, 0, stream>>>((const float4*)x, partial, bcnt, cand, bcap);
    select_apply<<<SBLOCKS, THREADS, 0, stream>>>((const float4*)x, partial, bcnt, cand,
                                                  bcap, w, b, (float4*)out, (float)cst);
}